// Round 16
// baseline (5574.018 us; speedup 1.0000x reference)
//
#include <hip/hip_runtime.h>
#include <hip/hip_cooperative_groups.h>
#include <hip/hip_bf16.h>

#define RFL(x) __builtin_amdgcn_readfirstlane(x)

typedef __attribute__((ext_vector_type(8))) short bf16x8;
typedef __attribute__((ext_vector_type(4))) float f32x4;

__device__ __forceinline__ float sigm(float x) { return 1.0f / (1.0f + __expf(-x)); }

__device__ __forceinline__ ushort bf16_rne(float x) {
  __hip_bfloat16 h = __float2bfloat16(x);
  return *reinterpret_cast<ushort*>(&h);
}
__device__ __forceinline__ float bf16_tof(ushort u) {
  __hip_bfloat16 h = *reinterpret_cast<__hip_bfloat16*>(&u);
  return __bfloat162float(h);
}

// MALL (device-coherent) ops — correct across XCDs
__device__ __forceinline__ unsigned long long ld_agent_u64(const void* p) {
  return __hip_atomic_load((unsigned long long*)p, __ATOMIC_RELAXED, __HIP_MEMORY_SCOPE_AGENT);
}
__device__ __forceinline__ unsigned int ld_agent_u32(const unsigned int* p) {
  return __hip_atomic_load(p, __ATOMIC_RELAXED, __HIP_MEMORY_SCOPE_AGENT);
}
__device__ __forceinline__ float ld_agent_f32(const float* p) {
  return __hip_atomic_load((float*)p, __ATOMIC_RELAXED, __HIP_MEMORY_SCOPE_AGENT);
}
__device__ __forceinline__ void st_agent_u32(unsigned int* p, unsigned int v) {
  __hip_atomic_store(p, v, __ATOMIC_RELAXED, __HIP_MEMORY_SCOPE_AGENT);
}
__device__ __forceinline__ void st_agent_f32(float* p, float v) {
  __hip_atomic_store(p, v, __ATOMIC_RELAXED, __HIP_MEMORY_SCOPE_AGENT);
}
__device__ __forceinline__ void st_agent_u16(ushort* p, ushort v) {
  __hip_atomic_store(p, v, __ATOMIC_RELAXED, __HIP_MEMORY_SCOPE_AGENT);
}

// L2-scope ops — valid ONLY between blocks on the same XCD (runtime-verified)
__device__ __forceinline__ unsigned long long ld_l2_u64(const void* p) {
  return *(volatile const unsigned long long*)p;
}
__device__ __forceinline__ unsigned int ld_l2_u32(const unsigned int* p) {
  return *(volatile const unsigned int*)p;
}
__device__ __forceinline__ void st_l2_u32(unsigned int* p, unsigned int v) {
  *(volatile unsigned int*)p = v;
}

__device__ __forceinline__ unsigned int xcc_id() {
  unsigned int x;
  asm volatile("s_getreg_b32 %0, hwreg(HW_REG_XCC_ID)" : "=s"(x));
  return x;
}

// ---------------- KW: split Whh_f, Whh_b, Wih_f, Wih_b -> bf16 hi|lo WBS[m][2048][1024] ----------------
__global__ void __launch_bounds__(256) kw_split2(const float* __restrict__ Whh_f,
    const float* __restrict__ Whh_b, const float* __restrict__ Wih_f,
    const float* __restrict__ Wih_b, ushort* __restrict__ WBS) {
  int idx = blockIdx.x * 256 + threadIdx.x;   // m(2b) x row(2048) x k4(128)
  int m = idx >> 18;
  int r = (idx >> 7) & 2047;
  int k4 = idx & 127;
  const float* W = (m == 0) ? Whh_f : (m == 1) ? Whh_b : (m == 2) ? Wih_f : Wih_b;
  float4 v = *(const float4*)&W[(size_t)r * 512 + k4 * 4];
  ushort h0 = bf16_rne(v.x), h1 = bf16_rne(v.y), h2 = bf16_rne(v.z), h3 = bf16_rne(v.w);
  ushort l0 = bf16_rne(v.x - bf16_tof(h0));
  ushort l1 = bf16_rne(v.y - bf16_tof(h1));
  ushort l2 = bf16_rne(v.z - bf16_tof(h2));
  ushort l3 = bf16_rne(v.w - bf16_tof(h3));
  ushort* base = WBS + (size_t)m * 2048 * 1024 + (size_t)r * 1024;
  uint2 HI = { (uint)h0 | ((uint)h1 << 16), (uint)h2 | ((uint)h3 << 16) };
  uint2 LO = { (uint)l0 | ((uint)l1 << 16), (uint)l2 | ((uint)l3 << 16) };
  *(uint2*)(base + k4 * 4) = HI;
  *(uint2*)(base + 512 + k4 * 4) = LO;
}

// ---------------- shared producer: xg for (d, jt), steps [tlb, tle) of chunk cx ----------------
// XG layout: [d*32+tl][b 64][row 2048]
template<bool AGENT>
__device__ __forceinline__ void xg_produce(const ushort* __restrict__ WBS,
    const float* __restrict__ inputs,
    const float* __restrict__ bih_f, const float* __restrict__ bhh_f,
    const float* __restrict__ bih_b, const float* __restrict__ bhh_b,
    float* __restrict__ XGo, float* part,
    int d, int jt, int cx, int tlb, int tle, int tid, int kq, int l15, int l4) {
  bf16x8 Afr[4][4];
  const ushort* WB = WBS + (size_t)(2 + d) * 2048 * 1024;
  const int c32s[4] = { 2*kq, 2*kq + 1, 16 + 2*kq, 16 + 2*kq + 1 };
#pragma unroll
  for (int g = 0; g < 4; ++g)
#pragma unroll
    for (int s = 0; s < 4; ++s)
      Afr[g][s] = *(const bf16x8*)(WB + (size_t)(g * 512 + jt * 16 + l15) * 1024 + c32s[s] * 32 + 8 * l4);

  int jj_g = tid & 15, b_g = tid >> 4;          // b_g in [0,32)
  int j_g = jt * 16 + jj_g;
  const float* bih = d ? bih_b : bih_f;
  const float* bhh = d ? bhh_b : bhh_f;
  float bias[4];
#pragma unroll
  for (int g = 0; g < 4; ++g) bias[g] = bih[g * 512 + j_g] + bhh[g * 512 + j_g];

#pragma unroll 1
  for (int tl = tlb; tl < tle; ++tl) {
    int t = cx + tl;
    int pos = d ? (511 - t) : t;
    bf16x8 Bfr[4][4];
#pragma unroll
    for (int bt = 0; bt < 4; ++bt) {
      const float* bp = inputs + ((size_t)(bt * 16 + l15) * 512 + pos) * 512;
#pragma unroll
      for (int q = 0; q < 2; ++q) {
        int k0 = (2 * kq + q) * 32 + 8 * l4;
        float4 x0 = *(const float4*)(bp + k0);
        float4 x1 = *(const float4*)(bp + k0 + 4);
        float xv[8] = { x0.x, x0.y, x0.z, x0.w, x1.x, x1.y, x1.z, x1.w };
        union { bf16x8 v; ushort u[8]; } H, L;
#pragma unroll
        for (int e = 0; e < 8; ++e) {
          ushort hh = bf16_rne(xv[e]);
          H.u[e] = hh;
          L.u[e] = bf16_rne(xv[e] - bf16_tof(hh));
        }
        Bfr[bt][q] = H.v;
        Bfr[bt][2 + q] = L.v;
      }
    }
    f32x4 acc[4][4];
#pragma unroll
    for (int g = 0; g < 4; ++g)
#pragma unroll
      for (int bt = 0; bt < 4; ++bt) acc[g][bt] = (f32x4){0.f, 0.f, 0.f, 0.f};
#pragma unroll
    for (int pass = 0; pass < 2; ++pass) {
#pragma unroll
      for (int s = 0; s < 4; ++s) {
        int bs2 = pass ? (s ^ 2) : s;
#pragma unroll
        for (int g = 0; g < 4; ++g)
#pragma unroll
          for (int bt = 0; bt < 4; ++bt)
            acc[g][bt] = __builtin_amdgcn_mfma_f32_16x16x32_bf16(
                Afr[g][s], Bfr[bt][bs2], acc[g][bt], 0, 0, 0);
      }
    }
    __syncthreads();
#pragma unroll
    for (int g = 0; g < 4; ++g)
#pragma unroll
      for (int bt = 0; bt < 4; ++bt) {
        int w = ((kq * 4 + g) * 64 + bt * 16 + l15) * 20 + 4 * l4;
        *(f32x4*)&part[w] = acc[g][bt];
      }
    __syncthreads();
    size_t xgb = (size_t)(d * 32 + tl) * 64;
#pragma unroll
    for (int u = 0; u < 2; ++u) {
      int b = b_g + 32 * u;
#pragma unroll
      for (int g = 0; g < 4; ++g) {
        float pre = bias[g];
#pragma unroll
        for (int kqi = 0; kqi < 8; ++kqi)
          pre += part[((kqi * 4 + g) * 64 + b) * 20 + jj_g];
        if (AGENT) st_agent_f32(&XGo[(xgb + b) * 2048 + g * 512 + j_g], pre);
        else       XGo[(xgb + b) * 2048 + g * 512 + j_g] = pre;
      }
    }
  }
}

// ---------------- prologue: xg for chunk 0 ----------------
__global__ void __launch_bounds__(512, 1) k1_pro(const ushort* __restrict__ WBS,
    const float* __restrict__ inputs,
    const float* __restrict__ bih_f, const float* __restrict__ bhh_f,
    const float* __restrict__ bih_b, const float* __restrict__ bhh_b,
    float* __restrict__ XGo) {
  extern __shared__ float part[];
  int bid = blockIdx.x;
  int tid = threadIdx.x;
  int kq = RFL((int)(tid >> 6));
  int lane = tid & 63, l15 = lane & 15, l4 = lane >> 4;
  int jt = bid & 31, d = (bid >> 5) & 1, ts = bid >> 6;
  xg_produce<false>(WBS, inputs, bih_f, bhh_f, bih_b, bhh_b, XGo, part,
                    d, jt, 0, ts * 8, ts * 8 + 8, tid, kq, l15, l4);
}

// ---------------- SINGLE fused cooperative kernel: all 16 chunks ----------------
// r = bid & 7. r in {0,1}: DUAL-DIR consumer (jt=bid>>3, bs=r): per step runs
//   [poll_f -> compute_f -> publish_f][poll_b -> compute_b -> publish_b]; each dir's
//   publish->visibility + stragglers hide under the other dir's compute phase.
//   Step slots per (dir,bs) XCD-local L2 (runtime-verified; agent fallback).
// r in {2..7}: 192 producers; chunk c in 1..15 into buf[c&1] via AGENT stores.
__global__ void __launch_bounds__(512, 1) k2_fused(const ushort* __restrict__ WBS,
    const float* __restrict__ inputs, float* __restrict__ XGa, float* __restrict__ XGb,
    ushort* __restrict__ HTB, float* __restrict__ OUTT, float* __restrict__ Cws,
    unsigned int* __restrict__ Bar,
    const float* __restrict__ bih_f, const float* __restrict__ bhh_f,
    const float* __restrict__ bih_b, const float* __restrict__ bhh_b) {
  extern __shared__ float part[];
  int bid = blockIdx.x;
  int tid = threadIdx.x;
  int kq = RFL((int)(tid >> 6));
  int lane = tid & 63;
  int l15 = lane & 15, l4 = lane >> 4;
  int r = bid & 7;

  unsigned int* XTab  = Bar + 2048;             // one uint per bid
  unsigned int* prodS = Bar + 4096;             // 192 slots x 16 uints
  unsigned int* consS = Bar + 8192;             // 64 slots x 16 uints

  if (r >= 2) {                                 // -------- producer path (192) --------
    int pid = (bid >> 3) * 6 + (r - 2);         // [0,192)
    int d = pid & 1, jt = (pid >> 1) & 31, th = pid >> 6;   // th in {0,1,2}
    int tlb = th * 11;
    int tle = tlb + 11; if (tle > 32) tle = 32;
#pragma unroll 1
    for (int c = 1; c < 16; ++c) {
      // wait: all consumers finished chunk c-2 (consDone >= c-1); 64 slots, 1/lane
      if (tid < 64) {
        unsigned int v; int gg = 0;
        do {
          v = ld_agent_u32(&consS[lane * 16]);
          if (v < (unsigned int)(c - 1)) __builtin_amdgcn_s_sleep(8);
        } while (!__all((int)(v >= (unsigned int)(c - 1))) && ++gg < (1 << 16));
      }
      __syncthreads();
      float* xw = (c & 1) ? XGb : XGa;
      xg_produce<true>(WBS, inputs, bih_f, bhh_f, bih_b, bhh_b, xw, part,
                       d, jt, c * 32, tlb, tle, tid, kq, l15, l4);
      __syncthreads();   // drain agent stores before publishing
      if (tid == 0) st_agent_u32(&prodS[pid * 16], (unsigned int)c);
    }
    return;
  }

  // -------- consumer: (jt, bs=r), BOTH dirs --------
  int bs = r;
  int jt = bid >> 3;                            // [0,32)
  int cid = jt * 2 + bs;                        // [0,64)
  const int c32s[4] = { 2*kq, 2*kq + 1, 16 + 2*kq, 16 + 2*kq + 1 };

  // A-frags for BOTH dirs
  bf16x8 Afr[2][4][4];
#pragma unroll
  for (int dd = 0; dd < 2; ++dd) {
    const ushort* WB = WBS + (size_t)dd * 2048 * 1024;
#pragma unroll
    for (int g = 0; g < 4; ++g)
#pragma unroll
      for (int s = 0; s < 4; ++s)
        Afr[dd][g][s] = *(const bf16x8*)(WB + (size_t)(g * 512 + jt * 16 + l15) * 1024 + c32s[s] * 32 + 8 * l4);
  }

  int jj_g = tid & 15, b_l = tid >> 4;          // b_l in [0,32)
  int j_g = jt * 16 + jj_g;
  int bcol = bs * 32 + b_l;
  float cc[2] = { 0.f, 0.f };

  // read-side constants for the swizzled part layout
  int jl4 = jj_g >> 2, jreg = jj_g & 3;
  int btr = b_l >> 4;
  int rsw = (b_l & 15) ^ (jl4 << 2);
  int rbase = jl4 * 16 + rsw;

  int* flagsh = (int*)(part + 20480);

  // ---- runtime XCD-uniformity check among the 32 blocks sharing r ----
  unsigned int myx = xcc_id() + 1u;
  if (tid == 0) { st_agent_u32(&XTab[bid], myx); flagsh[0] = 1; }
  __syncthreads();
  if (tid < 64) {
    int k = lane & 31;
    unsigned int q; int gg = 0;
    do { q = ld_agent_u32(&XTab[r + 8 * k]); } while (q == 0u && ++gg < (1 << 20));
    if (!__all((int)(q == myx)) && lane == 0) flagsh[0] = 0;
  }
  __syncthreads();
  int fastu = RFL(flagsh[0]);
  __syncthreads();

  int pslot = lane & 31;
  bool own = (pslot == jt);

#pragma unroll 1
  for (int c = 0; c < 16; ++c) {
    // chunk gate: xg for chunk c ready; 192 producer slots, 3 per lane
    if (c > 0) {
      if (tid < 64) {
        unsigned int v; int gg = 0;
        do {
          unsigned int a0 = ld_agent_u32(&prodS[(lane * 3) * 16]);
          unsigned int a1 = ld_agent_u32(&prodS[(lane * 3 + 1) * 16]);
          unsigned int a2 = ld_agent_u32(&prodS[(lane * 3 + 2) * 16]);
          v = a0 < a1 ? a0 : a1; v = v < a2 ? v : a2;
        } while (!__all((int)(v >= (unsigned int)c)) && ++gg < (1 << 16));
      }
      __syncthreads();
    }
    const float* xgp = (c & 1) ? XGb : XGa;

#pragma unroll 1
    for (int tl = 0; tl < 32; ++tl) {
      int t = c * 32 + tl, p = t & 1;
      // ---- xg prefetch for BOTH dirs (agent, coalesced), issued before any poll
      float xg[2][4];
#pragma unroll
      for (int dd = 0; dd < 2; ++dd) {
        size_t xb = ((size_t)(dd * 32 + tl) * 64 + bcol) * 2048;
#pragma unroll
        for (int g = 0; g < 4; ++g)
          xg[dd][g] = ld_agent_f32(&xgp[xb + g * 512 + j_g]);
      }

#pragma unroll
      for (int dd = 0; dd < 2; ++dd) {
        unsigned int* slots = Bar + (size_t)(dd * 2 + bs) * 512;   // 32 slots x 16
        // ---- per-dir poll (all waves; flags published one opposite-phase ago)
        {
          unsigned int v; int gg = 0;
          if (fastu) {
            do { v = own ? 0xFFFFFFFFu : ld_l2_u32(&slots[pslot * 16]); }
            while (!__all((int)(v >= (unsigned int)t)) && ++gg < (1 << 14));
          } else {
            do { v = own ? 0xFFFFFFFFu : ld_agent_u32(&slots[pslot * 16]); }
            while (!__all((int)(v >= (unsigned int)t)) && ++gg < (1 << 14));
          }
        }
        // ---- B-frag h loads for dir dd
        const ushort* hb = HTB + (size_t)(p * 2 + dd) * 65536;
        bf16x8 Bfr[2][4];
#pragma unroll
        for (int bt = 0; bt < 2; ++bt)
#pragma unroll
          for (int s = 0; s < 4; ++s) {
            const ushort* fp = hb + (size_t)c32s[s] * 2048 + (bs * 32 + bt * 16 + l15) * 32 + 8 * l4;
            union { bf16x8 v; unsigned long long q[2]; } u;
            if (fastu) { u.q[0] = ld_l2_u64(fp); u.q[1] = ld_l2_u64(fp + 4); }
            else       { u.q[0] = ld_agent_u64(fp); u.q[1] = ld_agent_u64(fp + 4); }
            Bfr[bt][s] = u.v;
          }
        // ---- MFMA (2-pass split-bf16)
        f32x4 acc[4][2];
#pragma unroll
        for (int g = 0; g < 4; ++g)
#pragma unroll
          for (int bt = 0; bt < 2; ++bt) acc[g][bt] = (f32x4){0.f, 0.f, 0.f, 0.f};
#pragma unroll
        for (int pass = 0; pass < 2; ++pass) {
#pragma unroll
          for (int s = 0; s < 4; ++s) {
            int bs2 = pass ? (s ^ 2) : s;
#pragma unroll
            for (int g = 0; g < 4; ++g)
#pragma unroll
              for (int bt = 0; bt < 2; ++bt)
                acc[g][bt] = __builtin_amdgcn_mfma_f32_16x16x32_bf16(
                    Afr[dd][g][s], Bfr[bt][bs2], acc[g][bt], 0, 0, 0);
          }
        }
        // ---- part write (swizzled, conflict-free)
#pragma unroll
        for (int g = 0; g < 4; ++g)
#pragma unroll
          for (int bt = 0; bt < 2; ++bt) {
            int f4i = ((kq * 4 + g) * 2 + bt) * 64 + l4 * 16 + (l15 ^ (l4 << 2));
            *(f32x4*)&part[f4i * 4] = acc[g][bt];
          }
        __syncthreads();
        // ---- gate
        float pre[4];
#pragma unroll
        for (int g = 0; g < 4; ++g) {
          float a = xg[dd][g];
#pragma unroll
          for (int kqi = 0; kqi < 8; ++kqi)
            a += part[(((kqi * 4 + g) * 2 + btr) * 64 + rbase) * 4 + jreg];
          pre[g] = a;
        }
        float ig = sigm(pre[0]), fg = sigm(pre[1]), gv = tanhf(pre[2]), og = sigm(pre[3]);
        cc[dd] = fmaf(fg, cc[dd], ig * gv);
        float hval = og * tanhf(cc[dd]);
        ushort hh = bf16_rne(hval);
        ushort hl = bf16_rne(hval - bf16_tof(hh));
        ushort* hbn = HTB + (size_t)((p ^ 1) * 2 + dd) * 65536;
        size_t hoff = (size_t)(j_g >> 5) * 2048 + (size_t)bcol * 32 + (j_g & 31);
        if (fastu) { hbn[hoff] = hh; hbn[hoff + 16 * 2048] = hl; }
        else { st_agent_u16(hbn + hoff, hh); st_agent_u16(hbn + hoff + 16 * 2048, hl); }
        __syncthreads();   // drain h stores (vmcnt(0) per wave) + part reuse safety
        if (tid == 0) {
          if (fastu) st_l2_u32(&slots[jt * 16], (unsigned int)(t + 1));
          else       st_agent_u32(&slots[jt * 16], (unsigned int)(t + 1));
        }
        // OUTT store off the exchange critical path
        int pos = dd ? (511 - t) : t;
        OUTT[((size_t)(dd * 512 + pos) * 512 + j_g) * 64 + bcol] = hval;
      }
    }
    // chunk c fully consumed (both dirs)
    if (tid == 0) st_agent_u32(&consS[cid * 16], (unsigned int)(c + 1));
  }
#pragma unroll
  for (int dd = 0; dd < 2; ++dd)
    Cws[(size_t)(dd * 512 + j_g) * 64 + bcol] = cc[dd];
}

// ---------------- K3a: last-row masked scores ST[t][b] ----------------
__global__ void __launch_bounds__(256) k3a_scores(const float* __restrict__ OUTT, float* __restrict__ ST) {
  int wid = RFL((int)(threadIdx.x >> 6));
  int b = threadIdx.x & 63;
  int t = blockIdx.x * 4 + wid;
  float acc = 0.f;
  for (int dd = 0; dd < 2; ++dd) {
    size_t bt = (size_t)(dd * 512 + t)   * 512;
    size_t bl = (size_t)(dd * 512 + 511) * 512;
    for (int jj = 0; jj < 512; ++jj)
      acc = fmaf(OUTT[(bt + jj) * 64 + b], OUTT[(bl + jj) * 64 + b], acc);
  }
  float sc = acc * (1.0f / 32.0f);
  ST[t * 64 + b] = (sc > 0.1f) ? sc : -1000000.0f;
}

// ---------------- K3b: softmax over t per batch ----------------
__global__ void __launch_bounds__(64) k3b_softmax(const float* __restrict__ ST, float* __restrict__ WT) {
  int b = threadIdx.x;
  float mx = -3.0e38f;
  for (int t = 0; t < 512; ++t) mx = fmaxf(mx, ST[t * 64 + b]);
  float sum = 0.f;
  for (int t = 0; t < 512; ++t) sum += __expf(ST[t * 64 + b] - mx);
  float inv = 1.0f / sum;
  for (int t = 0; t < 512; ++t) WT[t * 64 + b] = __expf(ST[t * 64 + b] - mx) * inv;
}

// ---------------- K3c: context CTX[d*512+j][b] ----------------
__global__ void __launch_bounds__(256) k3c_ctx(const float* __restrict__ OUTT,
    const float* __restrict__ WT, float* __restrict__ CTX) {
  int bq = blockIdx.x;
  int d = bq >> 7, j0 = (bq & 127) * 4;
  int wid = RFL((int)(threadIdx.x >> 6));
  int b = threadIdx.x & 63;
  int j = j0 + wid;
  float acc = 0.f;
  for (int t = 0; t < 512; ++t)
    acc = fmaf(WT[t * 64 + b], OUTT[((size_t)(d * 512 + t) * 512 + j) * 64 + b], acc);
  CTX[(size_t)(d * 512 + j) * 64 + b] = acc;
}

// ---------------- K3d-pre: transpose W_out[256][1024] -> WoT[1024][256] ----------------
__global__ void __launch_bounds__(256) k3dpre(const float* __restrict__ Wout, float* __restrict__ WoT) {
  int o = threadIdx.x;
  int k0 = blockIdx.x * 64;
  for (int k = k0; k < k0 + 64; ++k)
    WoT[k * 256 + o] = Wout[(size_t)o * 1024 + k];
}

// ---------------- K3d: y[b][o] = ctx[b] . WoT[:,o] + b_out[o] ----------------
__global__ void __launch_bounds__(256) k3d_y(const float* __restrict__ CTX,
    const float* __restrict__ WoT, const float* __restrict__ bout, float* __restrict__ y) {
  __shared__ float lc[1024];
  int b = blockIdx.x, o = threadIdx.x;
  for (int k = threadIdx.x; k < 1024; k += 256) lc[k] = CTX[(size_t)k * 64 + b];
  __syncthreads();
  float acc = bout[o];
  for (int k = 0; k < 1024; ++k) acc = fmaf(lc[k], WoT[k * 256 + o], acc);
  y[b * 256 + o] = acc;
}

extern "C" void kernel_launch(void* const* d_in, const int* in_sizes, int n_in,
                              void* d_out, int out_size, void* d_ws, size_t ws_size,
                              hipStream_t stream) {
  (void)in_sizes; (void)n_in; (void)out_size; (void)ws_size;
  const float* inputs = (const float*)d_in[0];
  const float* Wih_f = (const float*)d_in[1];
  const float* Whh_f = (const float*)d_in[2];
  const float* bih_f = (const float*)d_in[3];
  const float* bhh_f = (const float*)d_in[4];
  const float* Wih_b = (const float*)d_in[5];
  const float* Whh_b = (const float*)d_in[6];
  const float* bih_b = (const float*)d_in[7];
  const float* bhh_b = (const float*)d_in[8];
  const float* Wout  = (const float*)d_in[9];
  const float* bout  = (const float*)d_in[10];
  float* y = (float*)d_out;

  float* ws = (float*)d_ws;
  size_t off = 0;
  float* XGa = ws + off; off += (size_t)2 * 32 * 2048 * 64;                    // 32 MB
  float* XGb = ws + off; off += (size_t)2 * 32 * 2048 * 64;                    // 32 MB
  float* OUTT= ws + off; off += (size_t)2 * 512 * 512 * 64;                    // 128 MB
  ushort* HTB = (ushort*)(ws + off); off += (size_t)2 * 2 * 64 * 512;          // 512 KB
  float* Cws = ws + off; off += (size_t)2 * 512 * 64;
  float* ST  = ws + off; off += (size_t)512 * 64;
  float* WT  = ws + off; off += (size_t)512 * 64;
  float* CTX = ws + off; off += (size_t)2 * 512 * 64;
  float* WoT = ws + off; off += (size_t)1024 * 256;
  ushort* WBS = (ushort*)(ws + off); off += (size_t)4 * 2048 * 1024 / 2;       // 16 MB
  unsigned int* Bar = (unsigned int*)(ws + off); off += 16384;                  // slots

  hipMemsetAsync(HTB, 0, (size_t)4 * 65536 * sizeof(ushort), stream);
  hipMemsetAsync(Cws, 0, (size_t)2 * 512 * 64 * sizeof(float), stream);
  hipMemsetAsync(Bar, 0, 65536, stream);

  const int ldsK = 8 * 4 * 64 * 20 * 4;   // 160 KB (producer path sizing)
  hipFuncSetAttribute(reinterpret_cast<const void*>(k2_fused),
                      hipFuncAttributeMaxDynamicSharedMemorySize, ldsK);
  hipFuncSetAttribute(reinterpret_cast<const void*>(k1_pro),
                      hipFuncAttributeMaxDynamicSharedMemorySize, ldsK);

  kw_split2<<<4096, 256, 0, stream>>>(Whh_f, Whh_b, Wih_f, Wih_b, WBS);
  k1_pro<<<256, 512, ldsK, stream>>>(WBS, inputs, bih_f, bhh_f, bih_b, bhh_b, XGa);

  void* args[] = { (void*)&WBS, (void*)&inputs, (void*)&XGa, (void*)&XGb,
                   (void*)&HTB, (void*)&OUTT, (void*)&Cws, (void*)&Bar,
                   (void*)&bih_f, (void*)&bhh_f, (void*)&bih_b, (void*)&bhh_b };
  hipLaunchCooperativeKernel(reinterpret_cast<void*>(k2_fused),
                             dim3(256), dim3(512), args, ldsK, stream);

  k3a_scores<<<128, 256, 0, stream>>>(OUTT, ST);
  k3b_softmax<<<1, 64, 0, stream>>>(ST, WT);
  k3c_ctx<<<256, 256, 0, stream>>>(OUTT, WT, CTX);
  k3dpre<<<16, 256, 0, stream>>>(Wout, WoT);
  k3d_y<<<64, 256, 0, stream>>>(CTX, WoT, bout, y);
}

// Round 17
// 3164.457 us; speedup vs baseline: 1.7614x; 1.7614x over previous
//
#include <hip/hip_runtime.h>
#include <hip/hip_cooperative_groups.h>
#include <hip/hip_bf16.h>

#define RFL(x) __builtin_amdgcn_readfirstlane(x)

typedef __attribute__((ext_vector_type(8))) short bf16x8;
typedef __attribute__((ext_vector_type(4))) float f32x4;

__device__ __forceinline__ float sigm(float x) { return 1.0f / (1.0f + __expf(-x)); }

__device__ __forceinline__ ushort bf16_rne(float x) {
  __hip_bfloat16 h = __float2bfloat16(x);
  return *reinterpret_cast<ushort*>(&h);
}
__device__ __forceinline__ float bf16_tof(ushort u) {
  __hip_bfloat16 h = *reinterpret_cast<__hip_bfloat16*>(&u);
  return __bfloat162float(h);
}

// MALL (device-coherent) ops — correct across XCDs
__device__ __forceinline__ unsigned long long ld_agent_u64(const void* p) {
  return __hip_atomic_load((unsigned long long*)p, __ATOMIC_RELAXED, __HIP_MEMORY_SCOPE_AGENT);
}
__device__ __forceinline__ unsigned int ld_agent_u32(const unsigned int* p) {
  return __hip_atomic_load(p, __ATOMIC_RELAXED, __HIP_MEMORY_SCOPE_AGENT);
}
__device__ __forceinline__ float ld_agent_f32(const float* p) {
  return __hip_atomic_load((float*)p, __ATOMIC_RELAXED, __HIP_MEMORY_SCOPE_AGENT);
}
__device__ __forceinline__ void st_agent_u32(unsigned int* p, unsigned int v) {
  __hip_atomic_store(p, v, __ATOMIC_RELAXED, __HIP_MEMORY_SCOPE_AGENT);
}
__device__ __forceinline__ void st_agent_f32(float* p, float v) {
  __hip_atomic_store(p, v, __ATOMIC_RELAXED, __HIP_MEMORY_SCOPE_AGENT);
}
__device__ __forceinline__ void st_agent_u16(ushort* p, ushort v) {
  __hip_atomic_store(p, v, __ATOMIC_RELAXED, __HIP_MEMORY_SCOPE_AGENT);
}

// L2-scope ops — valid ONLY between blocks on the same XCD (runtime-verified)
__device__ __forceinline__ unsigned long long ld_l2_u64(const void* p) {
  return *(volatile const unsigned long long*)p;
}
__device__ __forceinline__ unsigned int ld_l2_u32(const unsigned int* p) {
  return *(volatile const unsigned int*)p;
}
__device__ __forceinline__ void st_l2_u32(unsigned int* p, unsigned int v) {
  *(volatile unsigned int*)p = v;
}

__device__ __forceinline__ unsigned int xcc_id() {
  unsigned int x;
  asm volatile("s_getreg_b32 %0, hwreg(HW_REG_XCC_ID)" : "=s"(x));
  return x;
}

// ---------------- KW: split Whh_f, Whh_b, Wih_f, Wih_b -> bf16 hi|lo WBS[m][2048][1024] ----------------
__global__ void __launch_bounds__(256) kw_split2(const float* __restrict__ Whh_f,
    const float* __restrict__ Whh_b, const float* __restrict__ Wih_f,
    const float* __restrict__ Wih_b, ushort* __restrict__ WBS) {
  int idx = blockIdx.x * 256 + threadIdx.x;   // m(2b) x row(2048) x k4(128)
  int m = idx >> 18;
  int r = (idx >> 7) & 2047;
  int k4 = idx & 127;
  const float* W = (m == 0) ? Whh_f : (m == 1) ? Whh_b : (m == 2) ? Wih_f : Wih_b;
  float4 v = *(const float4*)&W[(size_t)r * 512 + k4 * 4];
  ushort h0 = bf16_rne(v.x), h1 = bf16_rne(v.y), h2 = bf16_rne(v.z), h3 = bf16_rne(v.w);
  ushort l0 = bf16_rne(v.x - bf16_tof(h0));
  ushort l1 = bf16_rne(v.y - bf16_tof(h1));
  ushort l2 = bf16_rne(v.z - bf16_tof(h2));
  ushort l3 = bf16_rne(v.w - bf16_tof(h3));
  ushort* base = WBS + (size_t)m * 2048 * 1024 + (size_t)r * 1024;
  uint2 HI = { (uint)h0 | ((uint)h1 << 16), (uint)h2 | ((uint)h3 << 16) };
  uint2 LO = { (uint)l0 | ((uint)l1 << 16), (uint)l2 | ((uint)l3 << 16) };
  *(uint2*)(base + k4 * 4) = HI;
  *(uint2*)(base + 512 + k4 * 4) = LO;
}

// ---------------- shared producer: xg for (d, jt), steps [tlb, tle) of chunk cx ----------------
// XG layout: [d*32+tl][b 64][row 2048]  (coalesced consumer reads)
template<bool AGENT>
__device__ __forceinline__ void xg_produce(const ushort* __restrict__ WBS,
    const float* __restrict__ inputs,
    const float* __restrict__ bih_f, const float* __restrict__ bhh_f,
    const float* __restrict__ bih_b, const float* __restrict__ bhh_b,
    float* __restrict__ XGo, float* part,
    int d, int jt, int cx, int tlb, int tle, int tid, int kq, int l15, int l4) {
  bf16x8 Afr[4][4];
  const ushort* WB = WBS + (size_t)(2 + d) * 2048 * 1024;
  const int c32s[4] = { 2*kq, 2*kq + 1, 16 + 2*kq, 16 + 2*kq + 1 };
#pragma unroll
  for (int g = 0; g < 4; ++g)
#pragma unroll
    for (int s = 0; s < 4; ++s)
      Afr[g][s] = *(const bf16x8*)(WB + (size_t)(g * 512 + jt * 16 + l15) * 1024 + c32s[s] * 32 + 8 * l4);

  int jj_g = tid & 15, b_g = tid >> 4;          // b_g in [0,32)
  int j_g = jt * 16 + jj_g;
  const float* bih = d ? bih_b : bih_f;
  const float* bhh = d ? bhh_b : bhh_f;
  float bias[4];
#pragma unroll
  for (int g = 0; g < 4; ++g) bias[g] = bih[g * 512 + j_g] + bhh[g * 512 + j_g];

#pragma unroll 1
  for (int tl = tlb; tl < tle; ++tl) {
    int t = cx + tl;
    int pos = d ? (511 - t) : t;
    bf16x8 Bfr[4][4];
#pragma unroll
    for (int bt = 0; bt < 4; ++bt) {
      const float* bp = inputs + ((size_t)(bt * 16 + l15) * 512 + pos) * 512;
#pragma unroll
      for (int q = 0; q < 2; ++q) {
        int k0 = (2 * kq + q) * 32 + 8 * l4;
        float4 x0 = *(const float4*)(bp + k0);
        float4 x1 = *(const float4*)(bp + k0 + 4);
        float xv[8] = { x0.x, x0.y, x0.z, x0.w, x1.x, x1.y, x1.z, x1.w };
        union { bf16x8 v; ushort u[8]; } H, L;
#pragma unroll
        for (int e = 0; e < 8; ++e) {
          ushort hh = bf16_rne(xv[e]);
          H.u[e] = hh;
          L.u[e] = bf16_rne(xv[e] - bf16_tof(hh));
        }
        Bfr[bt][q] = H.v;
        Bfr[bt][2 + q] = L.v;
      }
    }
    f32x4 acc[4][4];
#pragma unroll
    for (int g = 0; g < 4; ++g)
#pragma unroll
      for (int bt = 0; bt < 4; ++bt) acc[g][bt] = (f32x4){0.f, 0.f, 0.f, 0.f};
#pragma unroll
    for (int pass = 0; pass < 2; ++pass) {
#pragma unroll
      for (int s = 0; s < 4; ++s) {
        int bs2 = pass ? (s ^ 2) : s;
#pragma unroll
        for (int g = 0; g < 4; ++g)
#pragma unroll
          for (int bt = 0; bt < 4; ++bt)
            acc[g][bt] = __builtin_amdgcn_mfma_f32_16x16x32_bf16(
                Afr[g][s], Bfr[bt][bs2], acc[g][bt], 0, 0, 0);
      }
    }
    __syncthreads();
#pragma unroll
    for (int g = 0; g < 4; ++g)
#pragma unroll
      for (int bt = 0; bt < 4; ++bt) {
        int w = ((kq * 4 + g) * 64 + bt * 16 + l15) * 20 + 4 * l4;
        *(f32x4*)&part[w] = acc[g][bt];
      }
    __syncthreads();
    size_t xgb = (size_t)(d * 32 + tl) * 64;
#pragma unroll
    for (int u = 0; u < 2; ++u) {
      int b = b_g + 32 * u;
#pragma unroll
      for (int g = 0; g < 4; ++g) {
        float pre = bias[g];
#pragma unroll
        for (int kqi = 0; kqi < 8; ++kqi)
          pre += part[((kqi * 4 + g) * 64 + b) * 20 + jj_g];
        if (AGENT) st_agent_f32(&XGo[(xgb + b) * 2048 + g * 512 + j_g], pre);
        else       XGo[(xgb + b) * 2048 + g * 512 + j_g] = pre;
      }
    }
  }
}

// ---------------- prologue: xg for chunk 0 ----------------
__global__ void __launch_bounds__(512, 1) k1_pro(const ushort* __restrict__ WBS,
    const float* __restrict__ inputs,
    const float* __restrict__ bih_f, const float* __restrict__ bhh_f,
    const float* __restrict__ bih_b, const float* __restrict__ bhh_b,
    float* __restrict__ XGo) {
  extern __shared__ float part[];
  int bid = blockIdx.x;
  int tid = threadIdx.x;
  int kq = RFL((int)(tid >> 6));
  int lane = tid & 63, l15 = lane & 15, l4 = lane >> 4;
  int jt = bid & 31, d = (bid >> 5) & 1, ts = bid >> 6;
  xg_produce<false>(WBS, inputs, bih_f, bhh_f, bih_b, bhh_b, XGo, part,
                    d, jt, 0, ts * 8, ts * 8 + 8, tid, kq, l15, l4);
}

// ---------------- SINGLE fused cooperative kernel: all 16 chunks (R15 structure) ----------------
// r = bid & 7. r<4: consumer group (d=r&1, bs=r>>1), jt=bid>>3.
//   h exchange + step slots XCD-local L2 (runtime-verified; agent fallback).
//   xg DOUBLE-BUFFERED in registers: next step's agent loads issued at step top,
//   consumed next step -> MALL latency/jitter off the critical path.
// r>=4: producers; chunk c in 1..15 into buf[c&1] via AGENT stores; MALL chunk handshake.
__global__ void __launch_bounds__(512, 1) k2_fused(const ushort* __restrict__ WBS,
    const float* __restrict__ inputs, float* __restrict__ XGa, float* __restrict__ XGb,
    ushort* __restrict__ HTB, float* __restrict__ OUTT, float* __restrict__ Cws,
    unsigned int* __restrict__ Bar,
    const float* __restrict__ bih_f, const float* __restrict__ bhh_f,
    const float* __restrict__ bih_b, const float* __restrict__ bhh_b) {
  extern __shared__ float part[];
  int bid = blockIdx.x;
  int tid = threadIdx.x;
  int kq = RFL((int)(tid >> 6));
  int lane = tid & 63;
  int l15 = lane & 15, l4 = lane >> 4;
  int r = bid & 7;

  unsigned int* prodS = Bar + 4096;             // 128 slots x 16 uints
  unsigned int* consS = Bar + 8192;             // 128 slots x 16 uints

  if (r >= 4) {                                 // -------- producer path --------
    int pid = (bid >> 3) * 4 + (r - 4);         // [0,128)
    int d = pid & 1, jt = (pid >> 1) & 31, th = pid >> 6;
#pragma unroll 1
    for (int c = 1; c < 16; ++c) {
      if (tid < 64) {
        unsigned int v; int gg = 0;
        do {
          unsigned int a = ld_agent_u32(&consS[(lane * 2) * 16]);
          unsigned int b2 = ld_agent_u32(&consS[(lane * 2 + 1) * 16]);
          v = a < b2 ? a : b2;
          if (v < (unsigned int)(c - 1)) __builtin_amdgcn_s_sleep(8);
        } while (!__all((int)(v >= (unsigned int)(c - 1))) && ++gg < (1 << 16));
      }
      __syncthreads();
      float* xw = (c & 1) ? XGb : XGa;
      xg_produce<true>(WBS, inputs, bih_f, bhh_f, bih_b, bhh_b, xw, part,
                       d, jt, c * 32, th * 16, th * 16 + 16, tid, kq, l15, l4);
      __syncthreads();
      if (tid == 0) st_agent_u32(&prodS[pid * 16], (unsigned int)c);
    }
    return;
  }

  // -------- consumer: group (d, bs), j-tile jt --------
  int d = r & 1, bs = r >> 1;
  int jt = bid >> 3;                            // [0,32)
  int cid = (bid >> 3) * 4 + r;                 // [0,128)
  const int c32s[4] = { 2*kq, 2*kq + 1, 16 + 2*kq, 16 + 2*kq + 1 };

  bf16x8 Afr[4][4];
  const ushort* WB = WBS + (size_t)d * 2048 * 1024;
#pragma unroll
  for (int g = 0; g < 4; ++g)
#pragma unroll
    for (int s = 0; s < 4; ++s)
      Afr[g][s] = *(const bf16x8*)(WB + (size_t)(g * 512 + jt * 16 + l15) * 1024 + c32s[s] * 32 + 8 * l4);

  int jj_g = tid & 15, b_l = tid >> 4;
  int j_g = jt * 16 + jj_g;
  int bcol = bs * 32 + b_l;
  float cc = 0.f;

  // read-side constants for the swizzled part layout
  int jl4 = jj_g >> 2, jreg = jj_g & 3;
  int btr = b_l >> 4;
  int rsw = (b_l & 15) ^ (jl4 << 2);
  int rbase = jl4 * 16 + rsw;

  unsigned int* slots = Bar + (size_t)r * 512;
  unsigned int* XTab  = Bar + 2048;
  int* flagsh = (int*)(part + 20480);

  // ---- runtime XCD-uniformity check for the fast (L2) path ----
  unsigned int myx = xcc_id() + 1u;
  if (tid == 0) { st_agent_u32(&XTab[bid], myx); flagsh[0] = 1; }
  __syncthreads();
  if (tid < 64) {
    int k = lane & 31;
    unsigned int q; int gg = 0;
    do { q = ld_agent_u32(&XTab[r + 8 * k]); } while (q == 0u && ++gg < (1 << 20));
    if (!__all((int)(q == myx)) && lane == 0) flagsh[0] = 0;
  }
  __syncthreads();
  int fastu = RFL(flagsh[0]);
  __syncthreads();

  int pslot = lane & 31;
  bool own = (pslot == jt);

#pragma unroll 1
  for (int c = 0; c < 16; ++c) {
    // chunk gate: xg for chunk c ready (chunk 0 pre-produced by k1_pro)
    if (c > 0) {
      if (tid < 64) {
        unsigned int v; int gg = 0;
        do {
          unsigned int a = ld_agent_u32(&prodS[(lane * 2) * 16]);
          unsigned int b2 = ld_agent_u32(&prodS[(lane * 2 + 1) * 16]);
          v = a < b2 ? a : b2;
        } while (!__all((int)(v >= (unsigned int)c)) && ++gg < (1 << 16));
      }
      __syncthreads();
    }
    const float* xgp = (c & 1) ? XGb : XGa;

    // xg for the first step of this chunk (blocking load, 1 of 32 steps)
    float xgc[4];
    {
      size_t xb = ((size_t)(d * 32 + 0) * 64 + bcol) * 2048;
#pragma unroll
      for (int g = 0; g < 4; ++g)
        xgc[g] = ld_agent_f32(&xgp[xb + g * 512 + j_g]);
    }

#pragma unroll 1
    for (int tl = 0; tl < 32; ++tl) {
      int t = c * 32 + tl, p = t & 1;
      // ---- issue NEXT step's xg loads (full step of slack to return)
      float xgn[4];
      if (tl < 31) {
        size_t xb = ((size_t)(d * 32 + tl + 1) * 64 + bcol) * 2048;
#pragma unroll
        for (int g = 0; g < 4; ++g)
          xgn[g] = ld_agent_f32(&xgp[xb + g * 512 + j_g]);
      }
      // ---- step poll: all waves independently
      {
        unsigned int v; int gg = 0;
        if (fastu) {
          do { v = own ? 0xFFFFFFFFu : ld_l2_u32(&slots[pslot * 16]); }
          while (!__all((int)(v >= (unsigned int)t)) && ++gg < (1 << 13));
        } else {
          do { v = own ? 0xFFFFFFFFu : ld_agent_u32(&slots[pslot * 16]); }
          while (!__all((int)(v >= (unsigned int)t)) && ++gg < (1 << 13));
        }
      }
      // ---- B-frag h loads
      const ushort* hb = HTB + (size_t)(p * 2 + d) * 65536;
      bf16x8 Bfr[2][4];
#pragma unroll
      for (int bt = 0; bt < 2; ++bt)
#pragma unroll
        for (int s = 0; s < 4; ++s) {
          const ushort* fp = hb + (size_t)c32s[s] * 2048 + (bs * 32 + bt * 16 + l15) * 32 + 8 * l4;
          union { bf16x8 v; unsigned long long q[2]; } u;
          if (fastu) { u.q[0] = ld_l2_u64(fp); u.q[1] = ld_l2_u64(fp + 4); }
          else       { u.q[0] = ld_agent_u64(fp); u.q[1] = ld_agent_u64(fp + 4); }
          Bfr[bt][s] = u.v;
        }
      // ---- MFMA (2-pass split-bf16)
      f32x4 acc[4][2];
#pragma unroll
      for (int g = 0; g < 4; ++g)
#pragma unroll
        for (int bt = 0; bt < 2; ++bt) acc[g][bt] = (f32x4){0.f, 0.f, 0.f, 0.f};
#pragma unroll
      for (int pass = 0; pass < 2; ++pass) {
#pragma unroll
        for (int s = 0; s < 4; ++s) {
          int bs2 = pass ? (s ^ 2) : s;
#pragma unroll
          for (int g = 0; g < 4; ++g)
#pragma unroll
            for (int bt = 0; bt < 2; ++bt)
              acc[g][bt] = __builtin_amdgcn_mfma_f32_16x16x32_bf16(
                  Afr[g][s], Bfr[bt][bs2], acc[g][bt], 0, 0, 0);
        }
      }
      // ---- part write: swizzled f4 layout (conflict-free b128 writes)
#pragma unroll
      for (int g = 0; g < 4; ++g)
#pragma unroll
        for (int bt = 0; bt < 2; ++bt) {
          int f4i = ((kq * 4 + g) * 2 + bt) * 64 + l4 * 16 + (l15 ^ (l4 << 2));
          *(f32x4*)&part[f4i * 4] = acc[g][bt];
        }
      __syncthreads();
      // ---- gate (uses PRE-LOADED xgc)
      float pre[4];
#pragma unroll
      for (int g = 0; g < 4; ++g) {
        float a = xgc[g];
#pragma unroll
        for (int kqi = 0; kqi < 8; ++kqi)
          a += part[(((kqi * 4 + g) * 2 + btr) * 64 + rbase) * 4 + jreg];
        pre[g] = a;
      }
      float ig = sigm(pre[0]), fg = sigm(pre[1]), gv = tanhf(pre[2]), og = sigm(pre[3]);
      cc = fmaf(fg, cc, ig * gv);
      float hval = og * tanhf(cc);
      ushort hh = bf16_rne(hval);
      ushort hl = bf16_rne(hval - bf16_tof(hh));
      ushort* hbn = HTB + (size_t)((p ^ 1) * 2 + d) * 65536;
      size_t hoff = (size_t)(j_g >> 5) * 2048 + (size_t)bcol * 32 + (j_g & 31);
      if (fastu) { hbn[hoff] = hh; hbn[hoff + 16 * 2048] = hl; }
      else { st_agent_u16(hbn + hoff, hh); st_agent_u16(hbn + hoff + 16 * 2048, hl); }
      __syncthreads();   // drain h stores
      if (tid == 0) {
        if (fastu) st_l2_u32(&slots[jt * 16], (unsigned int)(t + 1));
        else       st_agent_u32(&slots[jt * 16], (unsigned int)(t + 1));
      }
      int pos = d ? (511 - t) : t;
      OUTT[((size_t)(d * 512 + pos) * 512 + j_g) * 64 + bcol] = hval;
      // rotate xg double-buffer (vmcnt wait for xgn lands here, ~a full step after issue)
      if (tl < 31) {
#pragma unroll
        for (int g = 0; g < 4; ++g) xgc[g] = xgn[g];
      }
    }
    // chunk c fully consumed
    if (tid == 0) st_agent_u32(&consS[cid * 16], (unsigned int)(c + 1));
  }
  Cws[(size_t)(d * 512 + j_g) * 64 + bcol] = cc;
}

// ---------------- K3a: last-row masked scores ST[t][b] ----------------
__global__ void __launch_bounds__(256) k3a_scores(const float* __restrict__ OUTT, float* __restrict__ ST) {
  int wid = RFL((int)(threadIdx.x >> 6));
  int b = threadIdx.x & 63;
  int t = blockIdx.x * 4 + wid;
  float acc = 0.f;
  for (int dd = 0; dd < 2; ++dd) {
    size_t bt = (size_t)(dd * 512 + t)   * 512;
    size_t bl = (size_t)(dd * 512 + 511) * 512;
    for (int jj = 0; jj < 512; ++jj)
      acc = fmaf(OUTT[(bt + jj) * 64 + b], OUTT[(bl + jj) * 64 + b], acc);
  }
  float sc = acc * (1.0f / 32.0f);
  ST[t * 64 + b] = (sc > 0.1f) ? sc : -1000000.0f;
}

// ---------------- K3b: softmax over t per batch ----------------
__global__ void __launch_bounds__(64) k3b_softmax(const float* __restrict__ ST, float* __restrict__ WT) {
  int b = threadIdx.x;
  float mx = -3.0e38f;
  for (int t = 0; t < 512; ++t) mx = fmaxf(mx, ST[t * 64 + b]);
  float sum = 0.f;
  for (int t = 0; t < 512; ++t) sum += __expf(ST[t * 64 + b] - mx);
  float inv = 1.0f / sum;
  for (int t = 0; t < 512; ++t) WT[t * 64 + b] = __expf(ST[t * 64 + b] - mx) * inv;
}

// ---------------- K3c: context CTX[d*512+j][b] ----------------
__global__ void __launch_bounds__(256) k3c_ctx(const float* __restrict__ OUTT,
    const float* __restrict__ WT, float* __restrict__ CTX) {
  int bq = blockIdx.x;
  int d = bq >> 7, j0 = (bq & 127) * 4;
  int wid = RFL((int)(threadIdx.x >> 6));
  int b = threadIdx.x & 63;
  int j = j0 + wid;
  float acc = 0.f;
  for (int t = 0; t < 512; ++t)
    acc = fmaf(WT[t * 64 + b], OUTT[((size_t)(d * 512 + t) * 512 + j) * 64 + b], acc);
  CTX[(size_t)(d * 512 + j) * 64 + b] = acc;
}

// ---------------- K3d-pre: transpose W_out[256][1024] -> WoT[1024][256] ----------------
__global__ void __launch_bounds__(256) k3dpre(const float* __restrict__ Wout, float* __restrict__ WoT) {
  int o = threadIdx.x;
  int k0 = blockIdx.x * 64;
  for (int k = k0; k < k0 + 64; ++k)
    WoT[k * 256 + o] = Wout[(size_t)o * 1024 + k];
}

// ---------------- K3d: y[b][o] = ctx[b] . WoT[:,o] + b_out[o] ----------------
__global__ void __launch_bounds__(256) k3d_y(const float* __restrict__ CTX,
    const float* __restrict__ WoT, const float* __restrict__ bout, float* __restrict__ y) {
  __shared__ float lc[1024];
  int b = blockIdx.x, o = threadIdx.x;
  for (int k = threadIdx.x; k < 1024; k += 256) lc[k] = CTX[(size_t)k * 64 + b];
  __syncthreads();
  float acc = bout[o];
  for (int k = 0; k < 1024; ++k) acc = fmaf(lc[k], WoT[k * 256 + o], acc);
  y[b * 256 + o] = acc;
}

extern "C" void kernel_launch(void* const* d_in, const int* in_sizes, int n_in,
                              void* d_out, int out_size, void* d_ws, size_t ws_size,
                              hipStream_t stream) {
  (void)in_sizes; (void)n_in; (void)out_size; (void)ws_size;
  const float* inputs = (const float*)d_in[0];
  const float* Wih_f = (const float*)d_in[1];
  const float* Whh_f = (const float*)d_in[2];
  const float* bih_f = (const float*)d_in[3];
  const float* bhh_f = (const float*)d_in[4];
  const float* Wih_b = (const float*)d_in[5];
  const float* Whh_b = (const float*)d_in[6];
  const float* bih_b = (const float*)d_in[7];
  const float* bhh_b = (const float*)d_in[8];
  const float* Wout  = (const float*)d_in[9];
  const float* bout  = (const float*)d_in[10];
  float* y = (float*)d_out;

  float* ws = (float*)d_ws;
  size_t off = 0;
  float* XGa = ws + off; off += (size_t)2 * 32 * 2048 * 64;                    // 32 MB
  float* XGb = ws + off; off += (size_t)2 * 32 * 2048 * 64;                    // 32 MB
  float* OUTT= ws + off; off += (size_t)2 * 512 * 512 * 64;                    // 128 MB
  ushort* HTB = (ushort*)(ws + off); off += (size_t)2 * 2 * 64 * 512;          // 512 KB
  float* Cws = ws + off; off += (size_t)2 * 512 * 64;
  float* ST  = ws + off; off += (size_t)512 * 64;
  float* WT  = ws + off; off += (size_t)512 * 64;
  float* CTX = ws + off; off += (size_t)2 * 512 * 64;
  float* WoT = ws + off; off += (size_t)1024 * 256;
  ushort* WBS = (ushort*)(ws + off); off += (size_t)4 * 2048 * 1024 / 2;       // 16 MB
  unsigned int* Bar = (unsigned int*)(ws + off); off += 16384;

  hipMemsetAsync(HTB, 0, (size_t)4 * 65536 * sizeof(ushort), stream);
  hipMemsetAsync(Cws, 0, (size_t)2 * 512 * 64 * sizeof(float), stream);
  hipMemsetAsync(Bar, 0, 65536, stream);

  const int ldsK = 8 * 4 * 64 * 20 * 4;   // 160 KB (producer path sizing)
  hipFuncSetAttribute(reinterpret_cast<const void*>(k2_fused),
                      hipFuncAttributeMaxDynamicSharedMemorySize, ldsK);
  hipFuncSetAttribute(reinterpret_cast<const void*>(k1_pro),
                      hipFuncAttributeMaxDynamicSharedMemorySize, ldsK);

  kw_split2<<<4096, 256, 0, stream>>>(Whh_f, Whh_b, Wih_f, Wih_b, WBS);
  k1_pro<<<256, 512, ldsK, stream>>>(WBS, inputs, bih_f, bhh_f, bih_b, bhh_b, XGa);

  void* args[] = { (void*)&WBS, (void*)&inputs, (void*)&XGa, (void*)&XGb,
                   (void*)&HTB, (void*)&OUTT, (void*)&Cws, (void*)&Bar,
                   (void*)&bih_f, (void*)&bhh_f, (void*)&bih_b, (void*)&bhh_b };
  hipLaunchCooperativeKernel(reinterpret_cast<void*>(k2_fused),
                             dim3(256), dim3(512), args, ldsK, stream);

  k3a_scores<<<128, 256, 0, stream>>>(OUTT, ST);
  k3b_softmax<<<1, 64, 0, stream>>>(ST, WT);
  k3c_ctx<<<256, 256, 0, stream>>>(OUTT, WT, CTX);
  k3dpre<<<16, 256, 0, stream>>>(Wout, WoT);
  k3d_y<<<64, 256, 0, stream>>>(CTX, WoT, bout, y);
}

// Round 18
// 3045.340 us; speedup vs baseline: 1.8303x; 1.0391x over previous
//
#include <hip/hip_runtime.h>
#include <hip/hip_cooperative_groups.h>
#include <hip/hip_bf16.h>

#define RFL(x) __builtin_amdgcn_readfirstlane(x)

typedef __attribute__((ext_vector_type(8))) short bf16x8;
typedef __attribute__((ext_vector_type(4))) float f32x4;

__device__ __forceinline__ float sigm(float x) { return 1.0f / (1.0f + __expf(-x)); }

__device__ __forceinline__ ushort bf16_rne(float x) {
  __hip_bfloat16 h = __float2bfloat16(x);
  return *reinterpret_cast<ushort*>(&h);
}
__device__ __forceinline__ float bf16_tof(ushort u) {
  __hip_bfloat16 h = *reinterpret_cast<__hip_bfloat16*>(&u);
  return __bfloat162float(h);
}

// MALL (device-coherent) ops — correct across XCDs
__device__ __forceinline__ unsigned long long ld_agent_u64(const void* p) {
  return __hip_atomic_load((unsigned long long*)p, __ATOMIC_RELAXED, __HIP_MEMORY_SCOPE_AGENT);
}
__device__ __forceinline__ unsigned int ld_agent_u32(const unsigned int* p) {
  return __hip_atomic_load(p, __ATOMIC_RELAXED, __HIP_MEMORY_SCOPE_AGENT);
}
__device__ __forceinline__ float ld_agent_f32(const float* p) {
  return __hip_atomic_load((float*)p, __ATOMIC_RELAXED, __HIP_MEMORY_SCOPE_AGENT);
}
__device__ __forceinline__ void st_agent_u32(unsigned int* p, unsigned int v) {
  __hip_atomic_store(p, v, __ATOMIC_RELAXED, __HIP_MEMORY_SCOPE_AGENT);
}
__device__ __forceinline__ void st_agent_f32(float* p, float v) {
  __hip_atomic_store(p, v, __ATOMIC_RELAXED, __HIP_MEMORY_SCOPE_AGENT);
}
__device__ __forceinline__ void st_agent_u16(ushort* p, ushort v) {
  __hip_atomic_store(p, v, __ATOMIC_RELAXED, __HIP_MEMORY_SCOPE_AGENT);
}

// L2-scope ops — valid ONLY between blocks on the same XCD (runtime-verified)
__device__ __forceinline__ unsigned long long ld_l2_u64(const void* p) {
  return *(volatile const unsigned long long*)p;
}
__device__ __forceinline__ unsigned int ld_l2_u32(const unsigned int* p) {
  return *(volatile const unsigned int*)p;
}
__device__ __forceinline__ void st_l2_u32(unsigned int* p, unsigned int v) {
  *(volatile unsigned int*)p = v;
}

__device__ __forceinline__ unsigned int xcc_id() {
  unsigned int x;
  asm volatile("s_getreg_b32 %0, hwreg(HW_REG_XCC_ID)" : "=s"(x));
  return x;
}

// ---------------- KW: split Whh_f, Whh_b, Wih_f, Wih_b -> bf16 hi|lo WBS[m][2048][1024] ----------------
__global__ void __launch_bounds__(256) kw_split2(const float* __restrict__ Whh_f,
    const float* __restrict__ Whh_b, const float* __restrict__ Wih_f,
    const float* __restrict__ Wih_b, ushort* __restrict__ WBS) {
  int idx = blockIdx.x * 256 + threadIdx.x;   // m(2b) x row(2048) x k4(128)
  int m = idx >> 18;
  int r = (idx >> 7) & 2047;
  int k4 = idx & 127;
  const float* W = (m == 0) ? Whh_f : (m == 1) ? Whh_b : (m == 2) ? Wih_f : Wih_b;
  float4 v = *(const float4*)&W[(size_t)r * 512 + k4 * 4];
  ushort h0 = bf16_rne(v.x), h1 = bf16_rne(v.y), h2 = bf16_rne(v.z), h3 = bf16_rne(v.w);
  ushort l0 = bf16_rne(v.x - bf16_tof(h0));
  ushort l1 = bf16_rne(v.y - bf16_tof(h1));
  ushort l2 = bf16_rne(v.z - bf16_tof(h2));
  ushort l3 = bf16_rne(v.w - bf16_tof(h3));
  ushort* base = WBS + (size_t)m * 2048 * 1024 + (size_t)r * 1024;
  uint2 HI = { (uint)h0 | ((uint)h1 << 16), (uint)h2 | ((uint)h3 << 16) };
  uint2 LO = { (uint)l0 | ((uint)l1 << 16), (uint)l2 | ((uint)l3 << 16) };
  *(uint2*)(base + k4 * 4) = HI;
  *(uint2*)(base + 512 + k4 * 4) = LO;
}

// ---------------- shared producer: xg for (d, jt), steps [tlb, tle) of chunk cx ----------------
// XG layout: [d*32+tl][b 64][row 2048]  (coalesced consumer reads)
template<bool AGENT>
__device__ __forceinline__ void xg_produce(const ushort* __restrict__ WBS,
    const float* __restrict__ inputs,
    const float* __restrict__ bih_f, const float* __restrict__ bhh_f,
    const float* __restrict__ bih_b, const float* __restrict__ bhh_b,
    float* __restrict__ XGo, float* part,
    int d, int jt, int cx, int tlb, int tle, int tid, int kq, int l15, int l4) {
  bf16x8 Afr[4][4];
  const ushort* WB = WBS + (size_t)(2 + d) * 2048 * 1024;
  const int c32s[4] = { 2*kq, 2*kq + 1, 16 + 2*kq, 16 + 2*kq + 1 };
#pragma unroll
  for (int g = 0; g < 4; ++g)
#pragma unroll
    for (int s = 0; s < 4; ++s)
      Afr[g][s] = *(const bf16x8*)(WB + (size_t)(g * 512 + jt * 16 + l15) * 1024 + c32s[s] * 32 + 8 * l4);

  int jj_g = tid & 15, b_g = tid >> 4;          // b_g in [0,32)
  int j_g = jt * 16 + jj_g;
  const float* bih = d ? bih_b : bih_f;
  const float* bhh = d ? bhh_b : bhh_f;
  float bias[4];
#pragma unroll
  for (int g = 0; g < 4; ++g) bias[g] = bih[g * 512 + j_g] + bhh[g * 512 + j_g];

#pragma unroll 1
  for (int tl = tlb; tl < tle; ++tl) {
    int t = cx + tl;
    int pos = d ? (511 - t) : t;
    bf16x8 Bfr[4][4];
#pragma unroll
    for (int bt = 0; bt < 4; ++bt) {
      const float* bp = inputs + ((size_t)(bt * 16 + l15) * 512 + pos) * 512;
#pragma unroll
      for (int q = 0; q < 2; ++q) {
        int k0 = (2 * kq + q) * 32 + 8 * l4;
        float4 x0 = *(const float4*)(bp + k0);
        float4 x1 = *(const float4*)(bp + k0 + 4);
        float xv[8] = { x0.x, x0.y, x0.z, x0.w, x1.x, x1.y, x1.z, x1.w };
        union { bf16x8 v; ushort u[8]; } H, L;
#pragma unroll
        for (int e = 0; e < 8; ++e) {
          ushort hh = bf16_rne(xv[e]);
          H.u[e] = hh;
          L.u[e] = bf16_rne(xv[e] - bf16_tof(hh));
        }
        Bfr[bt][q] = H.v;
        Bfr[bt][2 + q] = L.v;
      }
    }
    f32x4 acc[4][4];
#pragma unroll
    for (int g = 0; g < 4; ++g)
#pragma unroll
      for (int bt = 0; bt < 4; ++bt) acc[g][bt] = (f32x4){0.f, 0.f, 0.f, 0.f};
#pragma unroll
    for (int pass = 0; pass < 2; ++pass) {
#pragma unroll
      for (int s = 0; s < 4; ++s) {
        int bs2 = pass ? (s ^ 2) : s;
#pragma unroll
        for (int g = 0; g < 4; ++g)
#pragma unroll
          for (int bt = 0; bt < 4; ++bt)
            acc[g][bt] = __builtin_amdgcn_mfma_f32_16x16x32_bf16(
                Afr[g][s], Bfr[bt][bs2], acc[g][bt], 0, 0, 0);
      }
    }
    __syncthreads();
#pragma unroll
    for (int g = 0; g < 4; ++g)
#pragma unroll
      for (int bt = 0; bt < 4; ++bt) {
        int w = ((kq * 4 + g) * 64 + bt * 16 + l15) * 20 + 4 * l4;
        *(f32x4*)&part[w] = acc[g][bt];
      }
    __syncthreads();
    size_t xgb = (size_t)(d * 32 + tl) * 64;
#pragma unroll
    for (int u = 0; u < 2; ++u) {
      int b = b_g + 32 * u;
#pragma unroll
      for (int g = 0; g < 4; ++g) {
        float pre = bias[g];
#pragma unroll
        for (int kqi = 0; kqi < 8; ++kqi)
          pre += part[((kqi * 4 + g) * 64 + b) * 20 + jj_g];
        if (AGENT) st_agent_f32(&XGo[(xgb + b) * 2048 + g * 512 + j_g], pre);
        else       XGo[(xgb + b) * 2048 + g * 512 + j_g] = pre;
      }
    }
  }
}

// ---------------- prologue: xg for chunk 0 ----------------
__global__ void __launch_bounds__(512, 1) k1_pro(const ushort* __restrict__ WBS,
    const float* __restrict__ inputs,
    const float* __restrict__ bih_f, const float* __restrict__ bhh_f,
    const float* __restrict__ bih_b, const float* __restrict__ bhh_b,
    float* __restrict__ XGo) {
  extern __shared__ float part[];
  int bid = blockIdx.x;
  int tid = threadIdx.x;
  int kq = RFL((int)(tid >> 6));
  int lane = tid & 63, l15 = lane & 15, l4 = lane >> 4;
  int jt = bid & 31, d = (bid >> 5) & 1, ts = bid >> 6;
  xg_produce<false>(WBS, inputs, bih_f, bhh_f, bih_b, bhh_b, XGo, part,
                    d, jt, 0, ts * 8, ts * 8 + 8, tid, kq, l15, l4);
}

// ---------------- SINGLE fused cooperative kernel: all 16 chunks ----------------
// r = bid & 7. r<4: consumer group (d=r&1, bs=r>>1), jt=bid>>3.
//   PER-WAVE dependency poll: wave kq's ccat slices are produced by blocks jt in
//   {4kq..4kq+3} ONLY -> each wave polls its 4 source slots (not all 32); waves with
//   fast sources proceed to loads+MFMA+part while the straggler's wave alone waits.
//   h exchange + step slots XCD-local L2 (runtime-verified; agent fallback).
//   xg double-buffered in registers.
// r>=4: producers; chunk c in 1..15 into buf[c&1] via AGENT stores; MALL chunk handshake.
__global__ void __launch_bounds__(512, 1) k2_fused(const ushort* __restrict__ WBS,
    const float* __restrict__ inputs, float* __restrict__ XGa, float* __restrict__ XGb,
    ushort* __restrict__ HTB, float* __restrict__ OUTT, float* __restrict__ Cws,
    unsigned int* __restrict__ Bar,
    const float* __restrict__ bih_f, const float* __restrict__ bhh_f,
    const float* __restrict__ bih_b, const float* __restrict__ bhh_b) {
  extern __shared__ float part[];
  int bid = blockIdx.x;
  int tid = threadIdx.x;
  int kq = RFL((int)(tid >> 6));
  int lane = tid & 63;
  int l15 = lane & 15, l4 = lane >> 4;
  int r = bid & 7;

  unsigned int* prodS = Bar + 4096;             // 128 slots x 16 uints
  unsigned int* consS = Bar + 8192;             // 128 slots x 16 uints

  if (r >= 4) {                                 // -------- producer path --------
    int pid = (bid >> 3) * 4 + (r - 4);         // [0,128)
    int d = pid & 1, jt = (pid >> 1) & 31, th = pid >> 6;
#pragma unroll 1
    for (int c = 1; c < 16; ++c) {
      if (tid < 64) {
        unsigned int v; int gg = 0;
        do {
          unsigned int a = ld_agent_u32(&consS[(lane * 2) * 16]);
          unsigned int b2 = ld_agent_u32(&consS[(lane * 2 + 1) * 16]);
          v = a < b2 ? a : b2;
          if (v < (unsigned int)(c - 1)) __builtin_amdgcn_s_sleep(8);
        } while (!__all((int)(v >= (unsigned int)(c - 1))) && ++gg < (1 << 16));
      }
      __syncthreads();
      float* xw = (c & 1) ? XGb : XGa;
      xg_produce<true>(WBS, inputs, bih_f, bhh_f, bih_b, bhh_b, xw, part,
                       d, jt, c * 32, th * 16, th * 16 + 16, tid, kq, l15, l4);
      __syncthreads();
      if (tid == 0) st_agent_u32(&prodS[pid * 16], (unsigned int)c);
    }
    return;
  }

  // -------- consumer: group (d, bs), j-tile jt --------
  int d = r & 1, bs = r >> 1;
  int jt = bid >> 3;                            // [0,32)
  int cid = (bid >> 3) * 4 + r;                 // [0,128)
  const int c32s[4] = { 2*kq, 2*kq + 1, 16 + 2*kq, 16 + 2*kq + 1 };

  bf16x8 Afr[4][4];
  const ushort* WB = WBS + (size_t)d * 2048 * 1024;
#pragma unroll
  for (int g = 0; g < 4; ++g)
#pragma unroll
    for (int s = 0; s < 4; ++s)
      Afr[g][s] = *(const bf16x8*)(WB + (size_t)(g * 512 + jt * 16 + l15) * 1024 + c32s[s] * 32 + 8 * l4);

  int jj_g = tid & 15, b_l = tid >> 4;
  int j_g = jt * 16 + jj_g;
  int bcol = bs * 32 + b_l;
  float cc = 0.f;

  // read-side constants for the swizzled part layout
  int jl4 = jj_g >> 2, jreg = jj_g & 3;
  int btr = b_l >> 4;
  int rsw = (b_l & 15) ^ (jl4 << 2);
  int rbase = jl4 * 16 + rsw;

  unsigned int* slots = Bar + (size_t)r * 512;
  unsigned int* XTab  = Bar + 2048;
  int* flagsh = (int*)(part + 20480);

  // ---- runtime XCD-uniformity check for the fast (L2) path ----
  unsigned int myx = xcc_id() + 1u;
  if (tid == 0) { st_agent_u32(&XTab[bid], myx); flagsh[0] = 1; }
  __syncthreads();
  if (tid < 64) {
    int k = lane & 31;
    unsigned int q; int gg = 0;
    do { q = ld_agent_u32(&XTab[r + 8 * k]); } while (q == 0u && ++gg < (1 << 20));
    if (!__all((int)(q == myx)) && lane == 0) flagsh[0] = 0;
  }
  __syncthreads();
  int fastu = RFL(flagsh[0]);
  __syncthreads();

  // per-wave dependency: wave kq consumes j in [64*kq, 64*kq+64) -> blocks 4kq..4kq+3
  int psl = 4 * kq + (lane & 3);
  bool ownp = (psl == jt);

#pragma unroll 1
  for (int c = 0; c < 16; ++c) {
    // chunk gate: xg for chunk c ready (chunk 0 pre-produced by k1_pro)
    if (c > 0) {
      if (tid < 64) {
        unsigned int v; int gg = 0;
        do {
          unsigned int a = ld_agent_u32(&prodS[(lane * 2) * 16]);
          unsigned int b2 = ld_agent_u32(&prodS[(lane * 2 + 1) * 16]);
          v = a < b2 ? a : b2;
        } while (!__all((int)(v >= (unsigned int)c)) && ++gg < (1 << 16));
      }
      __syncthreads();
    }
    const float* xgp = (c & 1) ? XGb : XGa;

    // xg for the first step of this chunk (blocking load, 1 of 32 steps)
    float xgc[4];
    {
      size_t xb = ((size_t)(d * 32 + 0) * 64 + bcol) * 2048;
#pragma unroll
      for (int g = 0; g < 4; ++g)
        xgc[g] = ld_agent_f32(&xgp[xb + g * 512 + j_g]);
    }

#pragma unroll 1
    for (int tl = 0; tl < 32; ++tl) {
      int t = c * 32 + tl, p = t & 1;
      // ---- issue NEXT step's xg loads (full step of slack to return)
      float xgn[4];
      if (tl < 31) {
        size_t xb = ((size_t)(d * 32 + tl + 1) * 64 + bcol) * 2048;
#pragma unroll
        for (int g = 0; g < 4; ++g)
          xgn[g] = ld_agent_f32(&xgp[xb + g * 512 + j_g]);
      }
      // ---- PER-WAVE poll: only this wave's 4 source blocks
      {
        unsigned int v; int gg = 0;
        if (fastu) {
          do { v = ownp ? 0xFFFFFFFFu : ld_l2_u32(&slots[psl * 16]); }
          while (!__all((int)(v >= (unsigned int)t)) && ++gg < (1 << 13));
        } else {
          do { v = ownp ? 0xFFFFFFFFu : ld_agent_u32(&slots[psl * 16]); }
          while (!__all((int)(v >= (unsigned int)t)) && ++gg < (1 << 13));
        }
      }
      // ---- B-frag h loads (only this wave's slices; sources verified above)
      const ushort* hb = HTB + (size_t)(p * 2 + d) * 65536;
      bf16x8 Bfr[2][4];
#pragma unroll
      for (int bt = 0; bt < 2; ++bt)
#pragma unroll
        for (int s = 0; s < 4; ++s) {
          const ushort* fp = hb + (size_t)c32s[s] * 2048 + (bs * 32 + bt * 16 + l15) * 32 + 8 * l4;
          union { bf16x8 v; unsigned long long q[2]; } u;
          if (fastu) { u.q[0] = ld_l2_u64(fp); u.q[1] = ld_l2_u64(fp + 4); }
          else       { u.q[0] = ld_agent_u64(fp); u.q[1] = ld_agent_u64(fp + 4); }
          Bfr[bt][s] = u.v;
        }
      // ---- MFMA (2-pass split-bf16)
      f32x4 acc[4][2];
#pragma unroll
      for (int g = 0; g < 4; ++g)
#pragma unroll
        for (int bt = 0; bt < 2; ++bt) acc[g][bt] = (f32x4){0.f, 0.f, 0.f, 0.f};
#pragma unroll
      for (int pass = 0; pass < 2; ++pass) {
#pragma unroll
        for (int s = 0; s < 4; ++s) {
          int bs2 = pass ? (s ^ 2) : s;
#pragma unroll
          for (int g = 0; g < 4; ++g)
#pragma unroll
            for (int bt = 0; bt < 2; ++bt)
              acc[g][bt] = __builtin_amdgcn_mfma_f32_16x16x32_bf16(
                  Afr[g][s], Bfr[bt][bs2], acc[g][bt], 0, 0, 0);
        }
      }
      // ---- part write: swizzled f4 layout (conflict-free b128 writes)
#pragma unroll
      for (int g = 0; g < 4; ++g)
#pragma unroll
        for (int bt = 0; bt < 2; ++bt) {
          int f4i = ((kq * 4 + g) * 2 + bt) * 64 + l4 * 16 + (l15 ^ (l4 << 2));
          *(f32x4*)&part[f4i * 4] = acc[g][bt];
        }
      __syncthreads();
      // ---- gate (uses PRE-LOADED xgc)
      float pre[4];
#pragma unroll
      for (int g = 0; g < 4; ++g) {
        float a = xgc[g];
#pragma unroll
        for (int kqi = 0; kqi < 8; ++kqi)
          a += part[(((kqi * 4 + g) * 2 + btr) * 64 + rbase) * 4 + jreg];
        pre[g] = a;
      }
      float ig = sigm(pre[0]), fg = sigm(pre[1]), gv = tanhf(pre[2]), og = sigm(pre[3]);
      cc = fmaf(fg, cc, ig * gv);
      float hval = og * tanhf(cc);
      ushort hh = bf16_rne(hval);
      ushort hl = bf16_rne(hval - bf16_tof(hh));
      ushort* hbn = HTB + (size_t)((p ^ 1) * 2 + d) * 65536;
      size_t hoff = (size_t)(j_g >> 5) * 2048 + (size_t)bcol * 32 + (j_g & 31);
      if (fastu) { hbn[hoff] = hh; hbn[hoff + 16 * 2048] = hl; }
      else { st_agent_u16(hbn + hoff, hh); st_agent_u16(hbn + hoff + 16 * 2048, hl); }
      __syncthreads();   // drain h stores
      if (tid == 0) {
        if (fastu) st_l2_u32(&slots[jt * 16], (unsigned int)(t + 1));
        else       st_agent_u32(&slots[jt * 16], (unsigned int)(t + 1));
      }
      int pos = d ? (511 - t) : t;
      OUTT[((size_t)(d * 512 + pos) * 512 + j_g) * 64 + bcol] = hval;
      if (tl < 31) {
#pragma unroll
        for (int g = 0; g < 4; ++g) xgc[g] = xgn[g];
      }
    }
    // chunk c fully consumed
    if (tid == 0) st_agent_u32(&consS[cid * 16], (unsigned int)(c + 1));
  }
  Cws[(size_t)(d * 512 + j_g) * 64 + bcol] = cc;
}

// ---------------- K3a: last-row masked scores ST[t][b] ----------------
__global__ void __launch_bounds__(256) k3a_scores(const float* __restrict__ OUTT, float* __restrict__ ST) {
  int wid = RFL((int)(threadIdx.x >> 6));
  int b = threadIdx.x & 63;
  int t = blockIdx.x * 4 + wid;
  float acc = 0.f;
  for (int dd = 0; dd < 2; ++dd) {
    size_t bt = (size_t)(dd * 512 + t)   * 512;
    size_t bl = (size_t)(dd * 512 + 511) * 512;
    for (int jj = 0; jj < 512; ++jj)
      acc = fmaf(OUTT[(bt + jj) * 64 + b], OUTT[(bl + jj) * 64 + b], acc);
  }
  float sc = acc * (1.0f / 32.0f);
  ST[t * 64 + b] = (sc > 0.1f) ? sc : -1000000.0f;
}

// ---------------- K3b: softmax over t per batch ----------------
__global__ void __launch_bounds__(64) k3b_softmax(const float* __restrict__ ST, float* __restrict__ WT) {
  int b = threadIdx.x;
  float mx = -3.0e38f;
  for (int t = 0; t < 512; ++t) mx = fmaxf(mx, ST[t * 64 + b]);
  float sum = 0.f;
  for (int t = 0; t < 512; ++t) sum += __expf(ST[t * 64 + b] - mx);
  float inv = 1.0f / sum;
  for (int t = 0; t < 512; ++t) WT[t * 64 + b] = __expf(ST[t * 64 + b] - mx) * inv;
}

// ---------------- K3c: context CTX[d*512+j][b] ----------------
__global__ void __launch_bounds__(256) k3c_ctx(const float* __restrict__ OUTT,
    const float* __restrict__ WT, float* __restrict__ CTX) {
  int bq = blockIdx.x;
  int d = bq >> 7, j0 = (bq & 127) * 4;
  int wid = RFL((int)(threadIdx.x >> 6));
  int b = threadIdx.x & 63;
  int j = j0 + wid;
  float acc = 0.f;
  for (int t = 0; t < 512; ++t)
    acc = fmaf(WT[t * 64 + b], OUTT[((size_t)(d * 512 + t) * 512 + j) * 64 + b], acc);
  CTX[(size_t)(d * 512 + j) * 64 + b] = acc;
}

// ---------------- K3d-pre: transpose W_out[256][1024] -> WoT[1024][256] ----------------
__global__ void __launch_bounds__(256) k3dpre(const float* __restrict__ Wout, float* __restrict__ WoT) {
  int o = threadIdx.x;
  int k0 = blockIdx.x * 64;
  for (int k = k0; k < k0 + 64; ++k)
    WoT[k * 256 + o] = Wout[(size_t)o * 1024 + k];
}

// ---------------- K3d: y[b][o] = ctx[b] . WoT[:,o] + b_out[o] ----------------
__global__ void __launch_bounds__(256) k3d_y(const float* __restrict__ CTX,
    const float* __restrict__ WoT, const float* __restrict__ bout, float* __restrict__ y) {
  __shared__ float lc[1024];
  int b = blockIdx.x, o = threadIdx.x;
  for (int k = threadIdx.x; k < 1024; k += 256) lc[k] = CTX[(size_t)k * 64 + b];
  __syncthreads();
  float acc = bout[o];
  for (int k = 0; k < 1024; ++k) acc = fmaf(lc[k], WoT[k * 256 + o], acc);
  y[b * 256 + o] = acc;
}

extern "C" void kernel_launch(void* const* d_in, const int* in_sizes, int n_in,
                              void* d_out, int out_size, void* d_ws, size_t ws_size,
                              hipStream_t stream) {
  (void)in_sizes; (void)n_in; (void)out_size; (void)ws_size;
  const float* inputs = (const float*)d_in[0];
  const float* Wih_f = (const float*)d_in[1];
  const float* Whh_f = (const float*)d_in[2];
  const float* bih_f = (const float*)d_in[3];
  const float* bhh_f = (const float*)d_in[4];
  const float* Wih_b = (const float*)d_in[5];
  const float* Whh_b = (const float*)d_in[6];
  const float* bih_b = (const float*)d_in[7];
  const float* bhh_b = (const float*)d_in[8];
  const float* Wout  = (const float*)d_in[9];
  const float* bout  = (const float*)d_in[10];
  float* y = (float*)d_out;

  float* ws = (float*)d_ws;
  size_t off = 0;
  float* XGa = ws + off; off += (size_t)2 * 32 * 2048 * 64;                    // 32 MB
  float* XGb = ws + off; off += (size_t)2 * 32 * 2048 * 64;                    // 32 MB
  float* OUTT= ws + off; off += (size_t)2 * 512 * 512 * 64;                    // 128 MB
  ushort* HTB = (ushort*)(ws + off); off += (size_t)2 * 2 * 64 * 512;          // 512 KB
  float* Cws = ws + off; off += (size_t)2 * 512 * 64;
  float* ST  = ws + off; off += (size_t)512 * 64;
  float* WT  = ws + off; off += (size_t)512 * 64;
  float* CTX = ws + off; off += (size_t)2 * 512 * 64;
  float* WoT = ws + off; off += (size_t)1024 * 256;
  ushort* WBS = (ushort*)(ws + off); off += (size_t)4 * 2048 * 1024 / 2;       // 16 MB
  unsigned int* Bar = (unsigned int*)(ws + off); off += 16384;

  hipMemsetAsync(HTB, 0, (size_t)4 * 65536 * sizeof(ushort), stream);
  hipMemsetAsync(Cws, 0, (size_t)2 * 512 * 64 * sizeof(float), stream);
  hipMemsetAsync(Bar, 0, 65536, stream);

  const int ldsK = 8 * 4 * 64 * 20 * 4;   // 160 KB (producer path sizing)
  hipFuncSetAttribute(reinterpret_cast<const void*>(k2_fused),
                      hipFuncAttributeMaxDynamicSharedMemorySize, ldsK);
  hipFuncSetAttribute(reinterpret_cast<const void*>(k1_pro),
                      hipFuncAttributeMaxDynamicSharedMemorySize, ldsK);

  kw_split2<<<4096, 256, 0, stream>>>(Whh_f, Whh_b, Wih_f, Wih_b, WBS);
  k1_pro<<<256, 512, ldsK, stream>>>(WBS, inputs, bih_f, bhh_f, bih_b, bhh_b, XGa);

  void* args[] = { (void*)&WBS, (void*)&inputs, (void*)&XGa, (void*)&XGb,
                   (void*)&HTB, (void*)&OUTT, (void*)&Cws, (void*)&Bar,
                   (void*)&bih_f, (void*)&bhh_f, (void*)&bih_b, (void*)&bhh_b };
  hipLaunchCooperativeKernel(reinterpret_cast<void*>(k2_fused),
                             dim3(256), dim3(512), args, ldsK, stream);

  k3a_scores<<<128, 256, 0, stream>>>(OUTT, ST);
  k3b_softmax<<<1, 64, 0, stream>>>(ST, WT);
  k3c_ctx<<<256, 256, 0, stream>>>(OUTT, WT, CTX);
  k3dpre<<<16, 256, 0, stream>>>(Wout, WoT);
  k3d_y<<<64, 256, 0, stream>>>(CTX, WoT, bout, y);
}